// Round 13
// baseline (7664.038 us; speedup 1.0000x reference)
//
#include <hip/hip_runtime.h>

typedef _Float16 f16;
typedef __attribute__((ext_vector_type(8))) _Float16 half8;
typedef __attribute__((ext_vector_type(2))) _Float16 half2v;
typedef __attribute__((ext_vector_type(4))) float f32x4;
typedef __attribute__((ext_vector_type(4))) unsigned int u32x4;
typedef unsigned long long u64;

#define TSTEPS 1024

// ---- workspace layout (bytes) ----
static const size_t OFF_WP   = 0;          // f16 [128 ntile][26 ks][64 lane][8]   = 3,407,872
static const size_t OFF_BIAS = 3407872;    // f32 [2048] gate-interleaved          = 8,192
static const size_t OFF_EMBP = 3416064;    // f16 [1024 t][8 bg][32 kc][16 bl][8]  = 67,108,864
static const size_t OFF_V    = 70524928;   // f16 [1024 t][128 b][64 m]            = 16,777,216
static const size_t OFF_XPRH = 87302144;   // f16 [2 par][8 bg][72 kc][16 bl][8]   = 294,912
static const size_t OFF_MEM  = 87597056;   // f32 [128 b][128 n][64 m]             = 4,194,304
static const size_t OFF_HFLG = 91791360;   // u32 [8 g][16 ns][8 wav]              = 4,096
static const size_t OFF_RFLG = 91795456;   // u32 [8 g][16 ns]                     = 512
static const size_t OFF_WVP  = 91795968;   // f16 [4 nt][8 ks][64 lane][8]         = 32,768
static const size_t WS_NEED  = 91828736;

// ---------------- prologue kernels ----------------

__global__ void marnn_packw(const float* __restrict__ w_ih, const float* __restrict__ w_hh,
                            const float* __restrict__ b_ih, const float* __restrict__ b_hh,
                            f16* __restrict__ WP, float* __restrict__ biasP) {
  int idx = blockIdx.x * 256 + threadIdx.x;
  if (idx < 2048) {
    int j = idx >> 2, g = idx & 3, rg = g * 512 + j;
    biasP[idx] = b_ih[rg] + b_hh[rg];
  }
  if (idx >= 1703936) return;
  int e = idx & 7, l = (idx >> 3) & 63;
  int q = idx >> 9;
  int ks = q % 26; int ntile = q / 26;
  int n = ntile * 16 + (l & 15);
  int k = ks * 32 + (l >> 4) * 8 + e;
  int j2 = n >> 2, g2 = n & 3, rg2 = g2 * 512 + j2;
  float v = (k < 320) ? w_ih[(size_t)rg2 * 320 + k] : w_hh[(size_t)rg2 * 512 + (k - 320)];
  WP[idx] = (f16)v;
}

__global__ void marnn_packwv(const float* __restrict__ W_wv, f16* __restrict__ WVP) {
  int idx = blockIdx.x * 256 + threadIdx.x;
  if (idx >= 16384) return;
  int e = idx & 7, l = (idx >> 3) & 63, ks = (idx >> 9) & 7, nt = idx >> 12;
  int n = nt * 16 + (l & 15);
  int k = ks * 32 + (l >> 4) * 8 + e;
  WVP[idx] = (f16)W_wv[n * 256 + k];
}

__global__ void marnn_packemb(const float* __restrict__ embs, f16* __restrict__ embsP) {
  const long total8 = (long)1024 * 128 * 32;
  const long stride = (long)gridDim.x * blockDim.x;
  for (long i8 = (long)blockIdx.x * blockDim.x + threadIdx.x; i8 < total8; i8 += stride) {
    int bl = (int)(i8 & 15), kc = (int)((i8 >> 4) & 31), bg = (int)((i8 >> 9) & 7);
    long t = i8 >> 12;
    const float* s = embs + ((t * 128) + bg * 16 + bl) * 256 + kc * 8;
    f32x4 a = *(const f32x4*)s, b = *(const f32x4*)(s + 4);
    half8 h;
    h[0]=(f16)a[0]; h[1]=(f16)a[1]; h[2]=(f16)a[2]; h[3]=(f16)a[3];
    h[4]=(f16)b[0]; h[5]=(f16)b[1]; h[6]=(f16)b[2]; h[7]=(f16)b[3];
    *(half8*)(embsP + i8 * 8) = h;
  }
}

// v[t][b][m] = emb[t,b] @ W_wv^T + b_wv via MFMA (A = W fragment, D rows = m); f16 out
__global__ __launch_bounds__(256)
void marnn_vpre(const f16* __restrict__ embsP, const f16* __restrict__ WVP,
                const float* __restrict__ b_wv, f16* __restrict__ Vh) {
  const int tb = blockIdx.x;              // t*8 + bg
  const int wv = threadIdx.x >> 6, l = threadIdx.x & 63;
  half8 bf[8];
  #pragma unroll
  for (int ks = 0; ks < 8; ++ks)
    bf[ks] = *(const half8*)(WVP + ((size_t)(wv * 8 + ks) * 64 + l) * 8);
  const f16* ab = embsP + (size_t)tb * 4096;
  f32x4 acc = {0.f, 0.f, 0.f, 0.f};
  #pragma unroll
  for (int ks = 0; ks < 8; ++ks) {
    half8 af = *(const half8*)(ab + ((size_t)(ks * 4 + (l >> 4)) * 16 + (l & 15)) * 8);
    acc = __builtin_amdgcn_mfma_f32_16x16x32_f16(bf[ks], af, acc, 0, 0, 0);
  }
  const int b = (tb & 7) * 16 + (l & 15);
  const long t = tb >> 3;
  #pragma unroll
  for (int r = 0; r < 4; ++r) {
    int m = wv * 16 + (l >> 4) * 4 + r;
    Vh[((t * 128) + b) * 64 + m] = (f16)(acc[r] + b_wv[m]);
  }
}

__global__ void marnn_init(const float* __restrict__ h0, const float* __restrict__ r0,
                           f16* __restrict__ XPRH) {
  int idx = blockIdx.x * 256 + threadIdx.x;
  if (idx >= 147456) return;
  int e = idx & 7; int q = idx >> 7; int kcidx = q % 72;
  float v = (kcidx < 8) ? r0[kcidx * 8 + e] : h0[(kcidx - 8) * 8 + e];
  XPRH[idx] = (f16)v;
}

// ---------------- main persistent kernel ----------------

struct __align__(16) MarnnSMem {
  f16  whead[128 * 512];   // 131072 B, rotate-swizzled rows
  char xl[26624];          // X frags: [0..8K)=emb, [8K..10K)=r frags, [10K..26K)=h
  char un[4096];           // M scratch: vpart@0 (1KB), vred@1024 (2KB), vsec@3072 (256B)
};

__device__ __forceinline__ float marnn_dot8(half8 a, half8 b, float acc) {
#if __has_builtin(__builtin_amdgcn_fdot2)
  half2v a0 = {a[0],a[1]}, a1 = {a[2],a[3]}, a2 = {a[4],a[5]}, a3 = {a[6],a[7]};
  half2v b0 = {b[0],b[1]}, b1 = {b[2],b[3]}, b2 = {b[4],b[5]}, b3 = {b[6],b[7]};
  acc = __builtin_amdgcn_fdot2(a0, b0, acc, false);
  acc = __builtin_amdgcn_fdot2(a1, b1, acc, false);
  acc = __builtin_amdgcn_fdot2(a2, b2, acc, false);
  acc = __builtin_amdgcn_fdot2(a3, b3, acc, false);
#else
  #pragma unroll
  for (int e = 0; e < 8; ++e) acc += (float)a[e] * (float)b[e];
#endif
  return acc;
}

__device__ __forceinline__ float fast_sigmoid(float x) {
  return __builtin_amdgcn_rcpf(1.f + __expf(-x));
}
__device__ __forceinline__ float fast_tanh(float x) {
  return 1.f - 2.f * __builtin_amdgcn_rcpf(1.f + __expf(2.f * x));
}

// LLC-coherent primitives: agent-scope relaxed atomics (sc0+sc1, no cache fences)
__device__ __forceinline__ unsigned ld_flag(const unsigned* p) {
  return __hip_atomic_load(p, __ATOMIC_RELAXED, __HIP_MEMORY_SCOPE_AGENT);
}
__device__ __forceinline__ void st_flag(unsigned* p, unsigned v) {
  __hip_atomic_store(p, v, __ATOMIC_RELAXED, __HIP_MEMORY_SCOPE_AGENT);
}
__device__ __forceinline__ u64 ld_llc64(const void* p) {
  return __hip_atomic_load((const u64*)p, __ATOMIC_RELAXED, __HIP_MEMORY_SCOPE_AGENT);
}
__device__ __forceinline__ void st_llc32(void* p, unsigned v) {
  __hip_atomic_store((unsigned*)p, v, __ATOMIC_RELAXED, __HIP_MEMORY_SCOPE_AGENT);
}

// wave-level poll of one 64B line (16 flags) — used for r
__device__ __forceinline__ void poll16(const unsigned* line, unsigned ep) {
  int l = threadIdx.x & 63;
  for (;;) {
    unsigned v = (l < 16) ? ld_flag(line + l) : ep;
    if (__all((int)(v >= ep))) break;
    __builtin_amdgcn_s_sleep(1);
  }
  asm volatile("" ::: "memory");
}
// wave-level poll of 128 per-wave h flags (2 words/lane)
__device__ __forceinline__ void pollH(const unsigned* base, unsigned ep) {
  int l = threadIdx.x & 63;
  for (;;) {
    unsigned v0 = ld_flag(base + l);
    unsigned v1 = ld_flag(base + 64 + l);
    if (__all((int)((v0 >= ep) & (v1 >= ep)))) break;
    __builtin_amdgcn_s_sleep(1);
  }
  asm volatile("" ::: "memory");
}

union H2U { f16 f; unsigned short u; };

__global__ __launch_bounds__(512, 1)
void marnn_main(const int* __restrict__ ilen_p, const float* __restrict__ c0,
                const float* __restrict__ r0,
                const float* __restrict__ W_wa, const float* __restrict__ b_wa,
                const float* __restrict__ W_ra, const float* __restrict__ b_ra,
                float* __restrict__ out, char* __restrict__ ws) {
  __shared__ MarnnSMem sm;

  const f16*   WP    = (const f16*)(ws + OFF_WP);
  const float* biasP = (const float*)(ws + OFF_BIAS);
  const f16*   embsP = (const f16*)(ws + OFF_EMBP);
  const f16*   Vh    = (const f16*)(ws + OFF_V);
  f16*         XPRH  = (f16*)(ws + OFF_XPRH);
  float*       MEMB  = (float*)(ws + OFF_MEM);
  unsigned*    HFLG  = (unsigned*)(ws + OFF_HFLG);
  unsigned*    RFLG  = (unsigned*)(ws + OFF_RFLG);

  const int blk = blockIdx.x, tid = threadIdx.x;
  const int wav = tid >> 6, lane = tid & 63;
  const int g = blk & 7, ns = blk >> 3;    // XCD-affine group x n-slice
  const int ilen = ilen_p[0];
  unsigned* gfh = HFLG + g * 128;          // 128 per-wave h flags (2 lines)
  unsigned* gfr = RFLG + g * 16;           // 16 per-block r flags (1 line)

  // persistent weight fragments (A operand: this wave's 16 gate-rows)
  half8 bfr[26];
  {
    const f16* wpb = WP + ((size_t)(ns * 8 + wav) * 26) * 512 + lane * 8;
    #pragma unroll
    for (int ks = 0; ks < 26; ++ks) bfr[ks] = *(const half8*)(wpb + ks * 512);
  }

  auto loadWhead = [&](const float* Wsrc) {
    for (int i = tid; i < 8192; i += 512) {
      int n = i >> 6, slot = i & 63;
      const float* s = Wsrc + n * 512 + slot * 8;
      f32x4 a = *(const f32x4*)(s), b2 = *(const f32x4*)(s + 4);
      half8 hv;
      hv[0]=(f16)a[0]; hv[1]=(f16)a[1]; hv[2]=(f16)a[2]; hv[3]=(f16)a[3];
      hv[4]=(f16)b2[0]; hv[5]=(f16)b2[1]; hv[6]=(f16)b2[2]; hv[7]=(f16)b2[3];
      *(half8*)((char*)sm.whead + (n << 10) + (((slot + n) & 63) << 4)) = hv;
    }
  };
  loadWhead(ilen > 0 ? W_wa : W_ra);

  // initial X stage (t=0, parity 0): emb 8KB + h 16KB (plain loads: kernel-boundary coherent)
  {
    const u32x4* s0 = (const u32x4*)(embsP + ((size_t)0 * 8 + g) * 4096);
    ((u32x4*)sm.xl)[tid] = s0[tid];
    const u32x4* s1 = (const u32x4*)(XPRH + (((size_t)0 * 8 + g) * 72 + 8) * 128);
    u32x4* d1 = (u32x4*)(sm.xl + 10240);
    d1[tid * 2] = s1[tid * 2]; d1[tid * 2 + 1] = s1[tid * 2 + 1];
  }
  __syncthreads();

  // in-lane activation ownership (D = W·X^T): lane -> (batch = lane&15,
  // j = wav*4 + sel), gates i,f,g,o = acc[0..3]   [operand-swap verified r7]
  const int b_lane = lane & 15, sel = lane >> 4;
  const int jg = ns * 32 + wav * 4 + sel;          // j in [0,512)
  float c = c0[jg];
  const f32x4 bias4 = *(const f32x4*)(biasP + jg * 4);
  const float r0v = (tid < 64) ? r0[tid] : 0.f;
  const int b = g * 16 + ns;                       // this block's memory-head batch

  // M-phase constants (all threads: all-wave softmax)
  const float bw0 = b_wa[lane], bw1 = b_wa[lane + 64];
  const float br0 = b_ra[lane], br1 = b_ra[lane + 64];
  const int gn = (wav & 3) * 32 + (lane & 31);   // logit row
  const int kq = ((wav >> 2) << 1) | (lane >> 5); // k-quarter

  // r fragments = r0 through t <= ilen (registers; broadcast across batch)
  half8 rf0, rf1;
  #pragma unroll
  for (int e = 0; e < 8; ++e) {
    rf0[e] = (f16)r0[sel * 8 + e];
    rf1[e] = (f16)r0[32 + sel * 8 + e];
  }

  // ---- long-window prefetch registers (issued a full step ahead) ----
  u32x4 sa = {0u, 0u, 0u, 0u};                     // emb_{t+1} for staging at step t
  if (TSTEPS > 1)
    sa = ((const u32x4*)(embsP + ((size_t)1 * 8 + g) * 4096))[tid];
  half8 vh = {};                                   // V row for step t (write phase)
  if (ilen > 0 && wav == 4 && lane < 8)
    vh = *(const half8*)(Vh + ((size_t)0 * 128 + b) * 64 + lane * 8);

  for (int t = 0; t < TSTEPS; ++t) {
    const int par = t & 1, nxt = par ^ 1;
    const bool iswrite = (t < ilen);

    // ---------------- phase A: gates GEMM (D = W·X^T) ----------------
    f32x4 acc0 = {0.f, 0.f, 0.f, 0.f}, acc1 = {0.f, 0.f, 0.f, 0.f};
    const char* xb = sm.xl + sel * 256 + b_lane * 16;
    #pragma unroll
    for (int ks = 0; ks < 8; ++ks) {
      half8 af = *(const half8*)(xb + ks * 1024);
      if (ks & 1) acc1 = __builtin_amdgcn_mfma_f32_16x16x32_f16(bfr[ks], af, acc1, 0, 0, 0);
      else        acc0 = __builtin_amdgcn_mfma_f32_16x16x32_f16(bfr[ks], af, acc0, 0, 0, 0);
    }
    #pragma unroll
    for (int ks = 10; ks < 26; ++ks) {
      half8 af = *(const half8*)(xb + ks * 1024);
      if (ks & 1) acc1 = __builtin_amdgcn_mfma_f32_16x16x32_f16(bfr[ks], af, acc1, 0, 0, 0);
      else        acc0 = __builtin_amdgcn_mfma_f32_16x16x32_f16(bfr[ks], af, acc0, 0, 0, 0);
    }
    if (t <= ilen) {   // write phase + first read step: r = r0 in registers
      acc0 = __builtin_amdgcn_mfma_f32_16x16x32_f16(bfr[8], rf0, acc0, 0, 0, 0);
      acc1 = __builtin_amdgcn_mfma_f32_16x16x32_f16(bfr[9], rf1, acc1, 0, 0, 0);
    } else {
      // wave0 r-service AFTER its 24 MFMAs: detect latency hidden behind work
      if (wav == 0) {
        poll16(gfr, (unsigned)(t - ilen));
        const u64* rp = (const u64*)(XPRH + (((size_t)par * 8 + g) * 72) * 128
                                     + (lane >> 4) * 128 + (lane & 15) * 8);
        union { u64 u[2]; half8 h; } r0u, r1u;
        r0u.u[0] = ld_llc64(rp);       r0u.u[1] = ld_llc64(rp + 1);
        r1u.u[0] = ld_llc64(rp + 128); r1u.u[1] = ld_llc64(rp + 129);
        char* rdst = sm.xl + 8192 + (lane >> 4) * 256 + (lane & 15) * 16;
        *(half8*)rdst = r0u.h;
        *(half8*)(rdst + 1024) = r1u.h;
      }
      __syncthreads();   // (Sa) r fragments staged
      acc0 = __builtin_amdgcn_mfma_f32_16x16x32_f16(bfr[8], *(const half8*)(xb + 8 * 1024), acc0, 0, 0, 0);
      acc1 = __builtin_amdgcn_mfma_f32_16x16x32_f16(bfr[9], *(const half8*)(xb + 9 * 1024), acc1, 0, 0, 0);
    }
    const f32x4 acc = acc0 + acc1;

    // ---------------- in-lane activation + h post (per-wave flag) ----------------
    {
      float si = fast_sigmoid(acc[0] + bias4[0]);
      float sf = fast_sigmoid(acc[1] + bias4[1]);
      float so = fast_sigmoid(acc[3] + bias4[3]);
      c = sf * c + si * fast_tanh(acc[2] + bias4[2]);
      float h = so * fast_tanh(c);
      H2U cv; cv.f = (f16)h;
      unsigned hu = cv.u;
      unsigned pu = __shfl_down(hu, 16, 64);     // partner j+1 (sel+1)
      if (!(sel & 1))
        st_llc32(&XPRH[(((size_t)nxt * 8 + g) * 72 + 8 + (jg >> 3)) * 128 + b_lane * 8 + (jg & 7)],
                 hu | (pu << 16));
    }
    asm volatile("s_waitcnt vmcnt(0)" ::: "memory");       // THIS wave's h stores acked
    if (lane == 0) st_flag(gfh + ns * 8 + wav, (unsigned)(t + 1));
    if (wav == 0) pollH(gfh, (unsigned)(t + 1));
    __syncthreads();   // (S2) poll done; all waves finished xl reads

    // ---------------- staging: emb + bulk h -> xl; re-issue emb prefetch ----------------
    {
      const u64* s1 = (const u64*)(XPRH + (((size_t)nxt * 8 + g) * 72 + 8) * 128);
      u64 hb0 = ld_llc64(s1 + tid * 4 + 0), hb1 = ld_llc64(s1 + tid * 4 + 1);
      u64 hb2 = ld_llc64(s1 + tid * 4 + 2), hb3 = ld_llc64(s1 + tid * 4 + 3);
      ((u32x4*)sm.xl)[tid] = sa;             // emb_{t+1}
      u64* d1 = (u64*)(sm.xl + 10240);       // h_{t+1}
      d1[tid * 4 + 0] = hb0; d1[tid * 4 + 1] = hb1;
      d1[tid * 4 + 2] = hb2; d1[tid * 4 + 3] = hb3;
      if (t + 2 < TSTEPS)                    // full-step latency window
        sa = ((const u32x4*)(embsP + (((size_t)(t + 2) * 8) + g) * 4096))[tid];
    }
    __syncthreads();   // (S3) xl holds emb_{t+1} + h_{t+1}

    // coalesced h out-store from staged LDS (off critical path)
    {
      int ob = tid >> 5, ojj = tid & 31;
      int oj = ns * 32 + ojj;
      f16 hv2 = *(const f16*)(sm.xl + 10240 + (oj >> 3) * 256 + ob * 16 + (oj & 7) * 2);
      out[(size_t)t * 73728 + (g * 16 + ob) * 576 + oj] = (float)hv2;
    }

    // ---------------- phase M: memory head (each block: batch b) ----------------
    if (t == ilen) { loadWhead(W_ra); __syncthreads(); }
    float* vpart = (float*)sm.un;            // 1 KB: [2 kq-pair][128 n]
    float* vred  = (float*)(sm.un + 1024);   // 2 KB
    float* vsec  = (float*)(sm.un + 3072);   // 256 B
    {
      if (iswrite && wav == 4 && lane < 8) {
        f32x4 lo = {(float)vh[0], (float)vh[1], (float)vh[2], (float)vh[3]};
        f32x4 hi = {(float)vh[4], (float)vh[5], (float)vh[6], (float)vh[7]};
        *(f32x4*)(vsec + lane * 8) = lo;
        *(f32x4*)(vsec + lane * 8 + 4) = hi;
        if (t + 1 < ilen)                    // next step's V row: full-step window
          vh = *(const half8*)(Vh + ((size_t)(t + 1) * 128 + b) * 64 + lane * 8);
      }
      const char* wrow = (const char*)sm.whead + (gn << 10);
      const char* hbase = sm.xl + 10240 + ns * 16;
      float av0 = 0.f, av1 = 0.f;
      #pragma unroll
      for (int i = 0; i < 16; i += 2) {
        int s0 = kq * 16 + i;
        av0 = marnn_dot8(*(const half8*)(wrow + (((s0 + gn) & 63) << 4)),
                         *(const half8*)(hbase + s0 * 256), av0);
        av1 = marnn_dot8(*(const half8*)(wrow + (((s0 + 1 + gn) & 63) << 4)),
                         *(const half8*)(hbase + (s0 + 1) * 256), av1);
      }
      float av = av0 + av1;
      av += __shfl_xor(av, 32, 64);
      if (lane < 32) vpart[((wav >> 2) << 7) + gn] = av;
    }
    __syncthreads();   // (S4) vpart complete

    // all-wave redundant softmax (no pbuf, no extra barrier)
    float p0, p1;
    {
      float l0 = vpart[lane] + vpart[128 + lane] + (iswrite ? bw0 : br0);
      float l1 = vpart[64 + lane] + vpart[192 + lane] + (iswrite ? bw1 : br1);
      float mx = fmaxf(l0, l1);
      #pragma unroll
      for (int off = 32; off > 0; off >>= 1) mx = fmaxf(mx, __shfl_xor(mx, off, 64));
      float e0 = __expf(l0 - mx), e1 = __expf(l1 - mx);
      float s = e0 + e1;
      #pragma unroll
      for (int off = 32; off > 0; off >>= 1) s += __shfl_xor(s, off, 64);
      float inv = __builtin_amdgcn_rcpf(s);
      p0 = e0 * inv; p1 = e1 * inv;
    }

    if (iswrite) {
      // mem[b] += wa ⊗ v : thread -> (n = tid>>2, m-quarter = tid&3); L2-resident
      int n = tid >> 2;
      float pA = __shfl(p0, n & 63, 64);
      float pB = __shfl(p1, n & 63, 64);
      float p = (n < 64) ? pA : pB;
      float* mrow = MEMB + (((size_t)b) * 128 + n) * 64 + (tid & 3) * 16;
      const float* vv = vsec + (tid & 3) * 16;
      #pragma unroll
      for (int i2 = 0; i2 < 16; i2 += 4) {
        f32x4 mm = *(f32x4*)(mrow + i2);
        f32x4 v4 = *(const f32x4*)(vv + i2);
        mm = mm + p * v4;
        *(f32x4*)(mrow + i2) = mm;
      }
      if (tid < 64)
        out[(size_t)t * 73728 + b * 576 + 512 + tid] = r0v;
    } else {
      // r = ra · mem[b] : thread -> (m = tid&63, n-chunk = wav of 16)
      const int m = tid & 63;
      const float* mcol = MEMB + (((size_t)b) * 128 + wav * 16) * 64 + m;
      float a0 = 0.f, a1 = 0.f;
      #pragma unroll
      for (int n2 = 0; n2 < 16; n2 += 2) {
        float q0 = __shfl((wav < 4) ? p0 : p1, (wav * 16 + n2) & 63, 64);
        float q1 = __shfl((wav < 4) ? p0 : p1, (wav * 16 + n2 + 1) & 63, 64);
        a0 = fmaf(q0, mcol[n2 * 64], a0);
        a1 = fmaf(q1, mcol[(n2 + 1) * 64], a1);
      }
      vred[wav * 64 + m] = a0 + a1;
      __syncthreads();   // (S6)
      if (tid < 64) {
        float rv = 0.f;
        #pragma unroll
        for (int nc = 0; nc < 8; ++nc) rv += vred[nc * 64 + tid];
        H2U cr; cr.f = (f16)rv;
        unsigned ru = cr.u;
        unsigned rp2 = __shfl_down(ru, 1, 64);
        if (!(tid & 1))
          st_llc32(&XPRH[(((size_t)nxt * 8 + g) * 72 + (tid >> 3)) * 128 + ns * 8 + (tid & 7)],
                   ru | (rp2 << 16));
        asm volatile("s_waitcnt vmcnt(0)" ::: "memory");
        if (tid == 0) st_flag(gfr + ns, (unsigned)(t - ilen + 1));
        out[(size_t)t * 73728 + b * 576 + 512 + tid] = rv;
      }
      // no trailing barrier: waves 1-7 run ahead into A_{t+1}; wave 0's r-service
      // and barrier (Sa) re-converge the block.
    }
  }
}

// ---------------- host ----------------

extern "C" void kernel_launch(void* const* d_in, const int* in_sizes, int n_in,
                              void* d_out, int out_size, void* d_ws, size_t ws_size,
                              hipStream_t stream) {
  const float* embs = (const float*)d_in[0];
  const int*   ilen = (const int*)d_in[1];
  const float* w_ih = (const float*)d_in[2];
  const float* w_hh = (const float*)d_in[3];
  const float* b_ih = (const float*)d_in[4];
  const float* b_hh = (const float*)d_in[5];
  const float* h0   = (const float*)d_in[6];
  const float* c0   = (const float*)d_in[7];
  const float* r0   = (const float*)d_in[8];
  const float* W_wa = (const float*)d_in[9];
  const float* b_wa = (const float*)d_in[10];
  const float* W_wv = (const float*)d_in[11];
  const float* b_wv = (const float*)d_in[12];
  const float* W_ra = (const float*)d_in[13];
  const float* b_ra = (const float*)d_in[14];
  float* out = (float*)d_out;
  char* ws = (char*)d_ws;
  if (ws_size < WS_NEED) return;  // insufficient scratch: fail cleanly

  hipMemsetAsync(ws + OFF_MEM, 0, 4194304, stream);
  hipMemsetAsync(ws + OFF_HFLG, 0, 4608, stream);    // h + r epoch flags -> 0
  marnn_packw<<<6656, 256, 0, stream>>>(w_ih, w_hh, b_ih, b_hh,
                                        (f16*)(ws + OFF_WP), (float*)(ws + OFF_BIAS));
  marnn_packwv<<<64, 256, 0, stream>>>(W_wv, (f16*)(ws + OFF_WVP));
  marnn_packemb<<<2048, 256, 0, stream>>>(embs, (f16*)(ws + OFF_EMBP));
  marnn_vpre<<<8192, 256, 0, stream>>>((const f16*)(ws + OFF_EMBP), (const f16*)(ws + OFF_WVP),
                                       b_wv, (f16*)(ws + OFF_V));
  marnn_init<<<576, 256, 0, stream>>>(h0, r0, (f16*)(ws + OFF_XPRH));
  marnn_main<<<128, 512, 0, stream>>>(ilen, c0, r0, W_wa, b_wa, W_ra, b_ra, out, ws);
}

// Round 14
// 5248.122 us; speedup vs baseline: 1.4603x; 1.4603x over previous
//
#include <hip/hip_runtime.h>

typedef _Float16 f16;
typedef __attribute__((ext_vector_type(8))) _Float16 half8;
typedef __attribute__((ext_vector_type(2))) _Float16 half2v;
typedef __attribute__((ext_vector_type(4))) float f32x4;
typedef __attribute__((ext_vector_type(4))) unsigned int u32x4;
typedef unsigned long long u64;

#define TSTEPS 1024

// ---- workspace layout (bytes) ----
static const size_t OFF_WP   = 0;           // f16 [128 ntile][26 ks][64 lane][8]     = 3,407,872
static const size_t OFF_BIAS = 3407872;     // f32 [2048] gate-interleaved            = 8,192
static const size_t OFF_EMBP = 3416064;     // f16 [1024 t][8 bg][32 kc][16 bl][8]    = 67,108,864
static const size_t OFF_V    = 70524928;    // f32 [1024 t][128 b][64 m]              = 33,554,432
static const size_t OFF_XPRH = 104079360;   // f16 [2 par][8 bg][72 kc][16 bl][8]     = 294,912
static const size_t OFF_MEM  = 104374272;   // f32 [128 b][128 n][64 m]               = 4,194,304
static const size_t OFF_BAR  = 108568576;   // u32 flags[8 groups][32]: [0..15]=h, [16..31]=r
static const size_t OFF_WVP  = 108569600;   // f16 [4 nt][8 ks][64 lane][8]           = 32,768
static const size_t WS_NEED  = 108602368;

// ---------------- prologue kernels ----------------

__global__ void marnn_packw(const float* __restrict__ w_ih, const float* __restrict__ w_hh,
                            const float* __restrict__ b_ih, const float* __restrict__ b_hh,
                            f16* __restrict__ WP, float* __restrict__ biasP) {
  int idx = blockIdx.x * 256 + threadIdx.x;
  if (idx < 2048) {
    int j = idx >> 2, g = idx & 3, rg = g * 512 + j;
    biasP[idx] = b_ih[rg] + b_hh[rg];
  }
  if (idx >= 1703936) return;
  int e = idx & 7, l = (idx >> 3) & 63;
  int q = idx >> 9;
  int ks = q % 26; int ntile = q / 26;
  int n = ntile * 16 + (l & 15);
  int k = ks * 32 + (l >> 4) * 8 + e;
  int j2 = n >> 2, g2 = n & 3, rg2 = g2 * 512 + j2;
  float v = (k < 320) ? w_ih[(size_t)rg2 * 320 + k] : w_hh[(size_t)rg2 * 512 + (k - 320)];
  WP[idx] = (f16)v;
}

__global__ void marnn_packwv(const float* __restrict__ W_wv, f16* __restrict__ WVP) {
  int idx = blockIdx.x * 256 + threadIdx.x;
  if (idx >= 16384) return;
  int e = idx & 7, l = (idx >> 3) & 63, ks = (idx >> 9) & 7, nt = idx >> 12;
  int n = nt * 16 + (l & 15);
  int k = ks * 32 + (l >> 4) * 8 + e;
  WVP[idx] = (f16)W_wv[n * 256 + k];
}

// pack embeddings into fragment layout, half8-vectorized grid-stride
__global__ void marnn_packemb(const float* __restrict__ embs, f16* __restrict__ embsP) {
  const long total8 = (long)1024 * 128 * 32;
  const long stride = (long)gridDim.x * blockDim.x;
  for (long i8 = (long)blockIdx.x * blockDim.x + threadIdx.x; i8 < total8; i8 += stride) {
    int bl = (int)(i8 & 15), kc = (int)((i8 >> 4) & 31), bg = (int)((i8 >> 9) & 7);
    long t = i8 >> 12;
    const float* s = embs + ((t * 128) + bg * 16 + bl) * 256 + kc * 8;
    f32x4 a = *(const f32x4*)s, b = *(const f32x4*)(s + 4);
    half8 h;
    h[0]=(f16)a[0]; h[1]=(f16)a[1]; h[2]=(f16)a[2]; h[3]=(f16)a[3];
    h[4]=(f16)b[0]; h[5]=(f16)b[1]; h[6]=(f16)b[2]; h[7]=(f16)b[3];
    *(half8*)(embsP + i8 * 8) = h;
  }
}

// v[t][b][m] = emb[t,b] @ W_wv^T + b_wv via MFMA (A = W fragment, D rows = m); f32 out
__global__ __launch_bounds__(256)
void marnn_vpre(const f16* __restrict__ embsP, const f16* __restrict__ WVP,
                const float* __restrict__ b_wv, float* __restrict__ V) {
  const int tb = blockIdx.x;              // t*8 + bg
  const int wv = threadIdx.x >> 6, l = threadIdx.x & 63;
  half8 bf[8];
  #pragma unroll
  for (int ks = 0; ks < 8; ++ks)
    bf[ks] = *(const half8*)(WVP + ((size_t)(wv * 8 + ks) * 64 + l) * 8);
  const f16* ab = embsP + (size_t)tb * 4096;
  f32x4 acc = {0.f, 0.f, 0.f, 0.f};
  #pragma unroll
  for (int ks = 0; ks < 8; ++ks) {
    half8 af = *(const half8*)(ab + ((size_t)(ks * 4 + (l >> 4)) * 16 + (l & 15)) * 8);
    acc = __builtin_amdgcn_mfma_f32_16x16x32_f16(bf[ks], af, acc, 0, 0, 0);
  }
  const int b = (tb & 7) * 16 + (l & 15);
  const long t = tb >> 3;
  #pragma unroll
  for (int r = 0; r < 4; ++r) {
    int m = wv * 16 + (l >> 4) * 4 + r;
    V[((t * 128) + b) * 64 + m] = acc[r] + b_wv[m];
  }
}

__global__ void marnn_init(const float* __restrict__ h0, const float* __restrict__ r0,
                           f16* __restrict__ XPRH) {
  int idx = blockIdx.x * 256 + threadIdx.x;
  if (idx >= 147456) return;
  int e = idx & 7; int q = idx >> 7; int kcidx = q % 72;
  float v = (kcidx < 8) ? r0[kcidx * 8 + e] : h0[(kcidx - 8) * 8 + e];
  XPRH[idx] = (f16)v;
}

// ---------------- main persistent kernel (round-11 verbatim: measured 5.25 ms) ----------------

struct __align__(16) MarnnSMem {
  f16  whead[128 * 512];   // 131072 B, rotate-swizzled rows
  char xl[26624];          // X frags: [0..8K)=emb, [8K..10K)=r frags, [10K..26K)=h
  char un[4096];           // M scratch: pbuf@0, vpart@512, vred@1536, vsec@3584
};

__device__ __forceinline__ float marnn_dot8(half8 a, half8 b, float acc) {
#if __has_builtin(__builtin_amdgcn_fdot2)
  half2v a0 = {a[0],a[1]}, a1 = {a[2],a[3]}, a2 = {a[4],a[5]}, a3 = {a[6],a[7]};
  half2v b0 = {b[0],b[1]}, b1 = {b[2],b[3]}, b2 = {b[4],b[5]}, b3 = {b[6],b[7]};
  acc = __builtin_amdgcn_fdot2(a0, b0, acc, false);
  acc = __builtin_amdgcn_fdot2(a1, b1, acc, false);
  acc = __builtin_amdgcn_fdot2(a2, b2, acc, false);
  acc = __builtin_amdgcn_fdot2(a3, b3, acc, false);
#else
  #pragma unroll
  for (int e = 0; e < 8; ++e) acc += (float)a[e] * (float)b[e];
#endif
  return acc;
}

__device__ __forceinline__ float fast_sigmoid(float x) {
  return __builtin_amdgcn_rcpf(1.f + __expf(-x));
}
__device__ __forceinline__ float fast_tanh(float x) {
  return 1.f - 2.f * __builtin_amdgcn_rcpf(1.f + __expf(2.f * x));
}

// LLC-coherent primitives: agent-scope relaxed atomics (sc0+sc1, no cache fences)
__device__ __forceinline__ unsigned ld_flag(const unsigned* p) {
  return __hip_atomic_load(p, __ATOMIC_RELAXED, __HIP_MEMORY_SCOPE_AGENT);
}
__device__ __forceinline__ void st_flag(unsigned* p, unsigned v) {
  __hip_atomic_store(p, v, __ATOMIC_RELAXED, __HIP_MEMORY_SCOPE_AGENT);
}
__device__ __forceinline__ u64 ld_llc64(const void* p) {
  return __hip_atomic_load((const u64*)p, __ATOMIC_RELAXED, __HIP_MEMORY_SCOPE_AGENT);
}
__device__ __forceinline__ void st_llc32(void* p, unsigned v) {
  __hip_atomic_store((unsigned*)p, v, __ATOMIC_RELAXED, __HIP_MEMORY_SCOPE_AGENT);
}

// wave-level poll (callers gate to wave 0): lanes 0-15 watch one 64B flag line
__device__ __forceinline__ void poll16(const unsigned* line, unsigned ep) {
  int l = threadIdx.x & 63;
  for (;;) {
    unsigned v = (l < 16) ? ld_flag(line + l) : ep;
    if (__all((int)(v >= ep))) break;
    __builtin_amdgcn_s_sleep(1);
  }
  asm volatile("" ::: "memory");
}

union H2U { f16 f; unsigned short u; };

__global__ __launch_bounds__(512, 1)
void marnn_main(const int* __restrict__ ilen_p, const float* __restrict__ c0,
                const float* __restrict__ r0,
                const float* __restrict__ W_wa, const float* __restrict__ b_wa,
                const float* __restrict__ W_ra, const float* __restrict__ b_ra,
                float* __restrict__ out, char* __restrict__ ws) {
  __shared__ MarnnSMem sm;

  const f16*   WP    = (const f16*)(ws + OFF_WP);
  const float* biasP = (const float*)(ws + OFF_BIAS);
  const f16*   embsP = (const f16*)(ws + OFF_EMBP);
  const float* Vbuf  = (const float*)(ws + OFF_V);
  f16*         XPRH  = (f16*)(ws + OFF_XPRH);
  float*       MEMB  = (float*)(ws + OFF_MEM);
  unsigned*    FLAGS = (unsigned*)(ws + OFF_BAR);

  const int blk = blockIdx.x, tid = threadIdx.x;
  const int wav = tid >> 6, lane = tid & 63;
  const int g = blk & 7, ns = blk >> 3;    // XCD-affine group x n-slice
  const int ilen = ilen_p[0];
  unsigned* gfh = FLAGS + g * 32;          // h flags, one 64B line
  unsigned* gfr = gfh + 16;                // r flags, next 64B line

  // persistent weight fragments (A operand: this wave's 16 gate-rows)
  half8 bfr[26];
  {
    const f16* wpb = WP + ((size_t)(ns * 8 + wav) * 26) * 512 + lane * 8;
    #pragma unroll
    for (int ks = 0; ks < 26; ++ks) bfr[ks] = *(const half8*)(wpb + ks * 512);
  }

  auto loadWhead = [&](const float* Wsrc) {
    for (int i = tid; i < 8192; i += 512) {
      int n = i >> 6, slot = i & 63;
      const float* s = Wsrc + n * 512 + slot * 8;
      f32x4 a = *(const f32x4*)(s), b2 = *(const f32x4*)(s + 4);
      half8 hv;
      hv[0]=(f16)a[0]; hv[1]=(f16)a[1]; hv[2]=(f16)a[2]; hv[3]=(f16)a[3];
      hv[4]=(f16)b2[0]; hv[5]=(f16)b2[1]; hv[6]=(f16)b2[2]; hv[7]=(f16)b2[3];
      *(half8*)((char*)sm.whead + (n << 10) + (((slot + n) & 63) << 4)) = hv;
    }
  };
  loadWhead(ilen > 0 ? W_wa : W_ra);

  // initial X stage (t=0, parity 0): emb 8KB + h 16KB (plain loads: kernel-boundary coherent)
  {
    const u32x4* s0 = (const u32x4*)(embsP + ((size_t)0 * 8 + g) * 4096);
    ((u32x4*)sm.xl)[tid] = s0[tid];
    const u32x4* s1 = (const u32x4*)(XPRH + (((size_t)0 * 8 + g) * 72 + 8) * 128);
    u32x4* d1 = (u32x4*)(sm.xl + 10240);
    d1[tid * 2] = s1[tid * 2]; d1[tid * 2 + 1] = s1[tid * 2 + 1];
  }
  __syncthreads();

  // in-lane activation ownership (D = W·X^T): lane -> (batch = lane&15,
  // j = wav*4 + sel), gates i,f,g,o = acc[0..3]   [operand-swap verified r7]
  const int b_lane = lane & 15, sel = lane >> 4;
  const int jg = ns * 32 + wav * 4 + sel;          // j in [0,512)
  float c = c0[jg];
  const f32x4 bias4 = *(const f32x4*)(biasP + jg * 4);
  const float r0v = (tid < 64) ? r0[tid] : 0.f;
  const int b = g * 16 + ns;                       // this block's memory-head batch

  // M-phase constants: softmax biases (wave 0), GEMV thread mapping
  const float bw0 = b_wa[lane], bw1 = b_wa[lane + 64];
  const float br0 = b_ra[lane], br1 = b_ra[lane + 64];
  const int gn = (wav & 3) * 32 + (lane & 31);   // logit row
  const int kq = ((wav >> 2) << 1) | (lane >> 5); // k-quarter

  // r fragments = r0 through t <= ilen (registers; broadcast across batch)
  half8 rf0, rf1;
  #pragma unroll
  for (int e = 0; e < 8; ++e) {
    rf0[e] = (f16)r0[sel * 8 + e];
    rf1[e] = (f16)r0[32 + sel * 8 + e];
  }

  for (int t = 0; t < TSTEPS; ++t) {
    const int par = t & 1, nxt = par ^ 1;
    const bool iswrite = (t < ilen);

    // ---- top-of-step prefetches (hide HBM latency under phase A) ----
    u32x4 sa = {0u, 0u, 0u, 0u};
    if (t + 1 < TSTEPS)
      sa = ((const u32x4*)(embsP + (((size_t)(t + 1) * 8) + g) * 4096))[tid];
    f32x4 vv4 = {0.f, 0.f, 0.f, 0.f};
    if (iswrite && wav == 4 && lane < 16)
      vv4 = *(const f32x4*)(Vbuf + ((size_t)t * 128 + b) * 64 + lane * 4);

    // ---------------- phase A: gates GEMM (D = W·X^T) ----------------
    f32x4 acc0 = {0.f, 0.f, 0.f, 0.f}, acc1 = {0.f, 0.f, 0.f, 0.f};
    const char* xb = sm.xl + sel * 256 + b_lane * 16;
    #pragma unroll
    for (int ks = 0; ks < 8; ++ks) {
      half8 af = *(const half8*)(xb + ks * 1024);
      if (ks & 1) acc1 = __builtin_amdgcn_mfma_f32_16x16x32_f16(bfr[ks], af, acc1, 0, 0, 0);
      else        acc0 = __builtin_amdgcn_mfma_f32_16x16x32_f16(bfr[ks], af, acc0, 0, 0, 0);
    }
    #pragma unroll
    for (int ks = 10; ks < 26; ++ks) {
      half8 af = *(const half8*)(xb + ks * 1024);
      if (ks & 1) acc1 = __builtin_amdgcn_mfma_f32_16x16x32_f16(bfr[ks], af, acc1, 0, 0, 0);
      else        acc0 = __builtin_amdgcn_mfma_f32_16x16x32_f16(bfr[ks], af, acc0, 0, 0, 0);
    }
    if (t <= ilen) {   // write phase + first read step: r = r0 in registers
      acc0 = __builtin_amdgcn_mfma_f32_16x16x32_f16(bfr[8], rf0, acc0, 0, 0, 0);
      acc1 = __builtin_amdgcn_mfma_f32_16x16x32_f16(bfr[9], rf1, acc1, 0, 0, 0);
    } else {
      // wave0 r-service AFTER its 24 MFMAs: detect latency hidden behind work
      if (wav == 0) {
        poll16(gfr, (unsigned)(t - ilen));
        const u64* rp = (const u64*)(XPRH + (((size_t)par * 8 + g) * 72) * 128
                                     + (lane >> 4) * 128 + (lane & 15) * 8);
        union { u64 u[2]; half8 h; } r0u, r1u;
        r0u.u[0] = ld_llc64(rp);       r0u.u[1] = ld_llc64(rp + 1);
        r1u.u[0] = ld_llc64(rp + 128); r1u.u[1] = ld_llc64(rp + 129);
        char* rdst = sm.xl + 8192 + (lane >> 4) * 256 + (lane & 15) * 16;
        *(half8*)rdst = r0u.h;
        *(half8*)(rdst + 1024) = r1u.h;
      }
      __syncthreads();   // (Sa) r fragments staged
      acc0 = __builtin_amdgcn_mfma_f32_16x16x32_f16(bfr[8], *(const half8*)(xb + 8 * 1024), acc0, 0, 0, 0);
      acc1 = __builtin_amdgcn_mfma_f32_16x16x32_f16(bfr[9], *(const half8*)(xb + 9 * 1024), acc1, 0, 0, 0);
    }
    const f32x4 acc = acc0 + acc1;

    // ---------------- in-lane activation + h post (no gatebuf, no extra syncs) ----------------
    {
      float si = fast_sigmoid(acc[0] + bias4[0]);
      float sf = fast_sigmoid(acc[1] + bias4[1]);
      float so = fast_sigmoid(acc[3] + bias4[3]);
      c = sf * c + si * fast_tanh(acc[2] + bias4[2]);
      float h = so * fast_tanh(c);
      H2U cv; cv.f = (f16)h;
      unsigned hu = cv.u;
      unsigned pu = __shfl_down(hu, 16, 64);     // partner j+1 (sel+1)
      if (!(sel & 1))
        st_llc32(&XPRH[(((size_t)nxt * 8 + g) * 72 + 8 + (jg >> 3)) * 128 + b_lane * 8 + (jg & 7)],
                 hu | (pu << 16));
    }
    asm volatile("s_waitcnt vmcnt(0)" ::: "memory");   // h LLC stores acked (per wave)
    __syncthreads();   // (S1) all xl reads done; all h stores acked
    if (tid == 0) st_flag(gfh + ns, (unsigned)(t + 1));
    if (wav == 0) poll16(gfh, (unsigned)(t + 1));
    __syncthreads();   // (S2)

    // ---------------- staging: emb + bulk h -> xl ----------------
    {
      const u64* s1 = (const u64*)(XPRH + (((size_t)nxt * 8 + g) * 72 + 8) * 128);
      u64 hb0 = ld_llc64(s1 + tid * 4 + 0), hb1 = ld_llc64(s1 + tid * 4 + 1);
      u64 hb2 = ld_llc64(s1 + tid * 4 + 2), hb3 = ld_llc64(s1 + tid * 4 + 3);
      ((u32x4*)sm.xl)[tid] = sa;             // emb_{t+1}
      u64* d1 = (u64*)(sm.xl + 10240);       // h_{t+1}
      d1[tid * 4 + 0] = hb0; d1[tid * 4 + 1] = hb1;
      d1[tid * 4 + 2] = hb2; d1[tid * 4 + 3] = hb3;
    }
    __syncthreads();   // (S3) xl holds emb_{t+1} + h_{t+1}

    // coalesced h out-store from staged LDS (normal stores: off critical path)
    {
      int ob = tid >> 5, ojj = tid & 31;
      int oj = ns * 32 + ojj;
      f16 hv = *(const f16*)(sm.xl + 10240 + (oj >> 3) * 256 + ob * 16 + (oj & 7) * 2);
      out[(size_t)t * 73728 + (g * 16 + ob) * 576 + oj] = (float)hv;
    }

    // ---------------- phase M: memory head (each block: batch b) ----------------
    if (t == ilen) { loadWhead(W_ra); __syncthreads(); }
    float* pbuf  = (float*)sm.un;            // 512 B
    float* vpart = (float*)(sm.un + 512);    // 1 KB: [2 kq-pair][128 n]
    float* vred  = (float*)(sm.un + 1536);   // 2 KB
    float* vsec  = (float*)(sm.un + 3584);   // 256 B
    {
      if (iswrite && wav == 4 && lane < 16) *(f32x4*)(vsec + lane * 4) = vv4;
      const char* wrow = (const char*)sm.whead + (gn << 10);
      const char* hbase = sm.xl + 10240 + ns * 16;
      float av0 = 0.f, av1 = 0.f;
      #pragma unroll
      for (int i = 0; i < 16; i += 2) {
        int s0 = kq * 16 + i;
        av0 = marnn_dot8(*(const half8*)(wrow + (((s0 + gn) & 63) << 4)),
                         *(const half8*)(hbase + s0 * 256), av0);
        av1 = marnn_dot8(*(const half8*)(wrow + (((s0 + 1 + gn) & 63) << 4)),
                         *(const half8*)(hbase + (s0 + 1) * 256), av1);
      }
      float av = av0 + av1;
      av += __shfl_xor(av, 32, 64);
      if (lane < 32) vpart[((wav >> 2) << 7) + gn] = av;
    }
    __syncthreads();   // (S4) vpart complete
    if (wav == 0) {
      float l0 = vpart[lane] + vpart[128 + lane] + (iswrite ? bw0 : br0);
      float l1 = vpart[64 + lane] + vpart[192 + lane] + (iswrite ? bw1 : br1);
      float mx = fmaxf(l0, l1);
      #pragma unroll
      for (int off = 32; off > 0; off >>= 1) mx = fmaxf(mx, __shfl_xor(mx, off, 64));
      float e0 = __expf(l0 - mx), e1 = __expf(l1 - mx);
      float s = e0 + e1;
      #pragma unroll
      for (int off = 32; off > 0; off >>= 1) s += __shfl_xor(s, off, 64);
      float inv = __builtin_amdgcn_rcpf(s);
      pbuf[lane] = e0 * inv; pbuf[lane + 64] = e1 * inv;
    }
    __syncthreads();   // (S5) pbuf ready
    if (iswrite) {
      // mem[b] += wa ⊗ v : thread -> (n = tid>>2, m-quarter = tid&3); L2-resident
      float p = pbuf[tid >> 2];
      float* mrow = MEMB + (((size_t)b) * 128 + (tid >> 2)) * 64 + (tid & 3) * 16;
      const float* vv = vsec + (tid & 3) * 16;
      #pragma unroll
      for (int i2 = 0; i2 < 16; i2 += 4) {
        f32x4 mm = *(f32x4*)(mrow + i2);
        f32x4 v4 = *(const f32x4*)(vv + i2);
        mm = mm + p * v4;
        *(f32x4*)(mrow + i2) = mm;
      }
      if (tid < 64)
        out[(size_t)t * 73728 + b * 576 + 512 + tid] = r0v;
    } else {
      // r = ra · mem[b] : thread -> (m = tid&63, n-chunk = wav of 16)
      const int m = tid & 63;
      const float* mcol = MEMB + (((size_t)b) * 128 + wav * 16) * 64 + m;
      float a0 = 0.f, a1 = 0.f;
      #pragma unroll
      for (int n2 = 0; n2 < 16; n2 += 2) {
        a0 = fmaf(pbuf[wav * 16 + n2],     mcol[n2 * 64],       a0);
        a1 = fmaf(pbuf[wav * 16 + n2 + 1], mcol[(n2 + 1) * 64], a1);
      }
      vred[wav * 64 + m] = a0 + a1;
      __syncthreads();   // (S6)
      if (tid < 64) {
        float rv = 0.f;
        #pragma unroll
        for (int nc = 0; nc < 8; ++nc) rv += vred[nc * 64 + tid];
        H2U cr; cr.f = (f16)rv;
        unsigned ru = cr.u;
        unsigned rp2 = __shfl_down(ru, 1, 64);
        if (!(tid & 1))
          st_llc32(&XPRH[(((size_t)nxt * 8 + g) * 72 + (tid >> 3)) * 128 + ns * 8 + (tid & 7)],
                   ru | (rp2 << 16));
        asm volatile("s_waitcnt vmcnt(0)" ::: "memory");
        if (tid == 0) st_flag(gfr + ns, (unsigned)(t - ilen + 1));
        out[(size_t)t * 73728 + b * 576 + 512 + tid] = rv;
      }
      // no trailing barrier: waves 1-7 run ahead into A_{t+1}; wave 0's r-service
      // and barrier (Sa) re-converge the block.
    }
  }
}

// ---------------- host ----------------

extern "C" void kernel_launch(void* const* d_in, const int* in_sizes, int n_in,
                              void* d_out, int out_size, void* d_ws, size_t ws_size,
                              hipStream_t stream) {
  const float* embs = (const float*)d_in[0];
  const int*   ilen = (const int*)d_in[1];
  const float* w_ih = (const float*)d_in[2];
  const float* w_hh = (const float*)d_in[3];
  const float* b_ih = (const float*)d_in[4];
  const float* b_hh = (const float*)d_in[5];
  const float* h0   = (const float*)d_in[6];
  const float* c0   = (const float*)d_in[7];
  const float* r0   = (const float*)d_in[8];
  const float* W_wa = (const float*)d_in[9];
  const float* b_wa = (const float*)d_in[10];
  const float* W_wv = (const float*)d_in[11];
  const float* b_wv = (const float*)d_in[12];
  const float* W_ra = (const float*)d_in[13];
  const float* b_ra = (const float*)d_in[14];
  float* out = (float*)d_out;
  char* ws = (char*)d_ws;
  if (ws_size < WS_NEED) return;  // insufficient scratch: fail cleanly

  hipMemsetAsync(ws + OFF_MEM, 0, 4194304, stream);
  hipMemsetAsync(ws + OFF_BAR, 0, 1024, stream);
  marnn_packw<<<6656, 256, 0, stream>>>(w_ih, w_hh, b_ih, b_hh,
                                        (f16*)(ws + OFF_WP), (float*)(ws + OFF_BIAS));
  marnn_packwv<<<64, 256, 0, stream>>>(W_wv, (f16*)(ws + OFF_WVP));
  marnn_packemb<<<2048, 256, 0, stream>>>(embs, (f16*)(ws + OFF_EMBP));
  marnn_vpre<<<8192, 256, 0, stream>>>((const f16*)(ws + OFF_EMBP), (const f16*)(ws + OFF_WVP),
                                       b_wv, (float*)(ws + OFF_V));
  marnn_init<<<576, 256, 0, stream>>>(h0, r0, (f16*)(ws + OFF_XPRH));
  marnn_main<<<128, 512, 0, stream>>>(ilen, c0, r0, W_wa, b_wa, W_ra, b_ra, out, ws);
}